// Round 8
// baseline (18911.719 us; speedup 1.0000x reference)
//
#include <hip/hip_runtime.h>
#include <math.h>

#define BB   64
#define TENC 128
#define TDEC 64
#define DHH  1024
#define DVV  2048
#define NCHN 256
#define GG   8704   // 4*DV + 2*NCH
#define KTOT 3072   // DH + DV

typedef unsigned short u16;
typedef unsigned int   u32;
typedef unsigned long long u64;
typedef __bf16 bf16x8 __attribute__((ext_vector_type(8)));
typedef float  f32x4  __attribute__((ext_vector_type(4)));

__device__ __forceinline__ u16 f2bf(float f) {
    unsigned u = __float_as_uint(f);
    unsigned r = (u + 0x7fffu + ((u >> 16) & 1u)) >> 16;
    return (u16)r;
}
__device__ __forceinline__ float bf2f(u16 s) { return __uint_as_float(((unsigned)s) << 16); }
__device__ __forceinline__ float tanh_fast(float x) {
    float xc = fminf(fmaxf(x, -15.f), 15.f);
    float t = __expf(2.f * xc);
    return 1.f - 2.f * __builtin_amdgcn_rcpf(t + 1.f);
}
__device__ __forceinline__ float sigmoid_fast(float x) {
    float xc = fminf(fmaxf(x, -30.f), 30.f);
    return __builtin_amdgcn_rcpf(1.f + __expf(-xc));
}

// ---- sc1 (agent-scope, L2-bypassing) relaxed accessors: no fences ever ----
__device__ __forceinline__ float ldf(const float* p) {
    return __uint_as_float(__hip_atomic_load((u32*)p, __ATOMIC_RELAXED, __HIP_MEMORY_SCOPE_AGENT));
}
__device__ __forceinline__ void stf(float* p, float v) {
    __hip_atomic_store((u32*)p, __float_as_uint(v), __ATOMIC_RELAXED, __HIP_MEMORY_SCOPE_AGENT);
}
__device__ __forceinline__ u64 ld8(const u16* p) {
    return __hip_atomic_load((u64*)p, __ATOMIC_RELAXED, __HIP_MEMORY_SCOPE_AGENT);
}
__device__ __forceinline__ void st4(u16* p, u32 v) {
    __hip_atomic_store((u32*)p, v, __ATOMIC_RELAXED, __HIP_MEMORY_SCOPE_AGENT);
}

// ---- zero-fence grid barrier (round-7, proven) ----
__device__ __forceinline__ void gbar(int* flags, int* gens, int target) {
    __syncthreads();
    int tid = threadIdx.x;
    if (blockIdx.x == 0) {
        if (tid > 0 && tid < 256) {
            while (__hip_atomic_load(flags + tid * 32, __ATOMIC_RELAXED,
                                     __HIP_MEMORY_SCOPE_AGENT) < target)
                __builtin_amdgcn_s_sleep(2);
        }
        __syncthreads();
        if (tid < 8)
            __hip_atomic_store(gens + tid * 32, target, __ATOMIC_RELAXED,
                               __HIP_MEMORY_SCOPE_AGENT);
    } else {
        if (tid == 0) {
            __hip_atomic_store(flags + blockIdx.x * 32, target, __ATOMIC_RELAXED,
                               __HIP_MEMORY_SCOPE_AGENT);
            while (__hip_atomic_load(gens + (blockIdx.x & 7) * 32, __ATOMIC_RELAXED,
                                     __HIP_MEMORY_SCOPE_AGENT) < target)
                __builtin_amdgcn_s_sleep(2);
        }
        __syncthreads();
    }
}

// ===================== precompute kernels =====================

__global__ __launch_bounds__(256) void k_init2(float* c, u16* xh, u16* xl, int* bar) {
    int i = blockIdx.x * 256 + threadIdx.x;   // grid 768 -> 196608
    xh[i] = 0; xl[i] = 0;
    if (i < BB * DVV) c[i] = 0.f;
    if (i < 8448) bar[i] = 0;
}

template <bool LO>
__global__ __launch_bounds__(256) void k_cvt(const float* __restrict__ S1,
                                             const float* __restrict__ S2,
                                             int K1, int N, int K,
                                             u16* __restrict__ Dh,
                                             u16* __restrict__ Dl) {
    __shared__ float t[64][65];
    int n0 = blockIdx.x * 64, k0 = blockIdx.y * 64;
    int tid = threadIdx.x;
    int cn = tid & 63, r4 = tid >> 6;
#pragma unroll
    for (int p = 0; p < 16; ++p) {
        int kk = p * 4 + r4;
        int kg = k0 + kk;
        const float* src = (kg < K1) ? S1 + (size_t)kg * N : S2 + (size_t)(kg - K1) * N;
        t[kk][cn] = src[n0 + cn];
    }
    __syncthreads();
    int ck = tid & 63, n4 = tid >> 6;
#pragma unroll
    for (int p = 0; p < 16; ++p) {
        int nn = p * 4 + n4;
        float w = t[ck][nn];
        u16 hi = f2bf(w);
        size_t o = (size_t)(n0 + nn) * K + k0 + ck;
        Dh[o] = hi;
        if (LO) Dl[o] = f2bf(w - bf2f(hi));
    }
}

__global__ __launch_bounds__(256) void k_Pb(const float* __restrict__ enc,
                                            const float* __restrict__ W1,
                                            const float* __restrict__ b1,
                                            u16* __restrict__ Pb) {
    __shared__ float As[32][68];
    __shared__ float Bs[32][68];
    int j0 = blockIdx.x * 64;
    int m0 = blockIdx.y * 64;
    int tid = threadIdx.x;
    int jg = tid & 15, bg = tid >> 4;
    float acc[4][4] = {};
    for (int k0 = 0; k0 < DHH; k0 += 32) {
#pragma unroll
        for (int p = 0; p < 8; ++p) {
            int r = p * 8 + (tid >> 5);
            int kk = tid & 31;
            As[kk][r] = enc[(size_t)(m0 + r) * DHH + k0 + kk];
        }
#pragma unroll
        for (int p = 0; p < 8; ++p) {
            int kk = p * 4 + (tid >> 6);
            int jl = tid & 63;
            Bs[kk][jl] = W1[(size_t)(k0 + kk) * DHH + j0 + jl];
        }
        __syncthreads();
#pragma unroll
        for (int kk = 0; kk < 32; ++kk) {
            float4 a = *(const float4*)&As[kk][bg * 4];
            float4 b = *(const float4*)&Bs[kk][jg * 4];
            float av[4] = {a.x, a.y, a.z, a.w};
            float bv[4] = {b.x, b.y, b.z, b.w};
#pragma unroll
            for (int i = 0; i < 4; ++i)
#pragma unroll
                for (int j = 0; j < 4; ++j) acc[i][j] += av[i] * bv[j];
        }
        __syncthreads();
    }
    float4 bb = *(const float4*)&b1[j0 + jg * 4];
    float bia[4] = {bb.x, bb.y, bb.z, bb.w};
#pragma unroll
    for (int i = 0; i < 4; ++i) {
        int r = m0 + bg * 4 + i;
        ushort4 sv;
        sv.x = f2bf(acc[i][0] + bia[0]);
        sv.y = f2bf(acc[i][1] + bia[1]);
        sv.z = f2bf(acc[i][2] + bia[2]);
        sv.w = f2bf(acc[i][3] + bia[3]);
        *(ushort4*)&Pb[(size_t)r * DHH + j0 + jg * 4] = sv;
    }
}

// ===================== persistent decode kernel =====================
// Cached (never invalidated): Wth/Wtl/Wta, Pbf, enc, w2, bih, bhh, c(block-local), out.
// sc1 (fabric): hWp, xh/xl, gp, flags/gens.
// Odd LDS pitches (21 / 53 sixteen-byte units) -> conflict-free ds_read_b128.

__global__ __launch_bounds__(512, 2) void k_decode(
        const u16* Pbf, float* hWp, float* gp, float* c,
        u16* xh, u16* xl,
        const u16* __restrict__ Wth, const u16* __restrict__ Wtl,
        const u16* __restrict__ Wta,
        const float* __restrict__ enc, const float* __restrict__ w2,
        const float* __restrict__ bih, const float* __restrict__ bhh,
        float* out, int* bar) {
    __shared__ u64 smem8[13568];   // 108,544 B, reused per phase
    float* smf = (float*)smem8;
    int* flags = bar;
    int* gens = bar + 8192;
    int blk = blockIdx.x, tid = threadIdx.x;
    int wv = tid >> 6, l = tid & 63;
    int lr = l & 15, lk4 = l >> 4;
    f32x4 z = {0.f, 0.f, 0.f, 0.f};
    int bt = 1;

    for (int t = 0; t < TDEC; ++t) {
        // ---------- phase A: hW partials (16 n-tiles x 16 ksegs of 128) ----------
        {
            int nt = blk & 15, kseg = blk >> 4;
            int wn = wv & 3, kh = wv >> 2;
            // stage x h-slice [64 rows x 128 cols hi] -> LDS, pitch 21 units (336B)
            u16* lsa = (u16*)smem8;
            for (int u = tid; u < 1024; u += 512) {
                int row = u >> 4, cu = u & 15;
                const u16* gs = xh + (size_t)row * KTOT + 1024 + kseg * 128 + cu * 8;
                u64 a0 = ld8(gs), a1 = ld8(gs + 4);
                u16* d = lsa + ((row * 21 + cu) << 3);
                *(u64*)d = a0; *(u64*)(d + 4) = a1;
            }
            __syncthreads();
            int n = nt * 64 + wn * 16 + lr;
            const u16* wp = Wta + (size_t)n * 2048 + kseg * 128 + kh * 64 + lk4 * 8;
            bf16x8 w0 = *(const bf16x8*)(wp);
            bf16x8 w1 = *(const bf16x8*)(wp + 32);
            f32x4 acc[4] = {z, z, z, z};
#pragma unroll
            for (int mf = 0; mf < 4; ++mf) {
                int row = mf * 16 + lr;
                int unit = kh * 8 + lk4;
                bf16x8 a = *(const bf16x8*)(lsa + ((row * 21 + unit) << 3));
                acc[mf] = __builtin_amdgcn_mfma_f32_16x16x32_bf16(a, w0, acc[mf], 0, 0, 0);
            }
#pragma unroll
            for (int mf = 0; mf < 4; ++mf) {
                int row = mf * 16 + lr;
                int unit = kh * 8 + lk4 + 4;
                bf16x8 a = *(const bf16x8*)(lsa + ((row * 21 + unit) << 3));
                acc[mf] = __builtin_amdgcn_mfma_f32_16x16x32_bf16(a, w1, acc[mf], 0, 0, 0);
            }
            float* red = (float*)((char*)smem8 + 21504);   // 64 x 68
            if (kh == 0) {
#pragma unroll
                for (int mf = 0; mf < 4; ++mf)
#pragma unroll
                    for (int r = 0; r < 4; ++r)
                        red[(mf * 16 + lk4 * 4 + r) * 68 + wn * 16 + lr] = acc[mf][r];
            }
            __syncthreads();
            if (kh == 1) {
#pragma unroll
                for (int mf = 0; mf < 4; ++mf)
#pragma unroll
                    for (int r = 0; r < 4; ++r) {
                        int m = mf * 16 + lk4 * 4 + r;
                        stf(&hWp[(size_t)(kseg * 64 + m) * DHH + n],
                            acc[mf][r] + red[m * 68 + wn * 16 + lr]);
                    }
            }
        }
        gbar(flags, gens, bt++);

        // ---------- phase BC (blocks 0..63 = batch b): e, softmax, context ----------
        if (blk < BB) {
            int b = blk;
            float* hw  = smf;             // 1024
            float* w2s = smf + 1024;      // 1024
            float* er  = smf + 2048;      // 128
            float* al  = smf + 2176;      // 128
            float* red = smf + 2304;      // 512
            float* pr  = smf + 2816;      // 8192
#pragma unroll
            for (int p = 0; p < 2; ++p) {
                int d = p * 512 + tid;
                float s = 0.f;
#pragma unroll
                for (int ks = 0; ks < 16; ++ks) s += ldf(&hWp[(size_t)(ks * 64 + b) * DHH + d]);
                hw[d] = s;
                w2s[d] = w2[d];
            }
            __syncthreads();
            const u16* Pb = Pbf + (size_t)b * TENC * DHH;
#pragma unroll
            for (int i = 0; i < 16; ++i) {
                int tt = wv * 16 + i;
                const u16* Pr = Pb + (size_t)tt * DHH;
                float s = 0.f;
#pragma unroll
                for (int q = 0; q < 16; ++q) {
                    int d = q * 64 + l;
                    s += tanh_fast(bf2f(Pr[d]) + hw[d]) * w2s[d];
                }
#pragma unroll
                for (int off = 32; off > 0; off >>= 1) s += __shfl_down(s, off);
                if (l == 0) er[tt] = s;
            }
            __syncthreads();
            float v = (tid < TENC) ? er[tid] : -3.0e38f;
            red[tid] = v;
            __syncthreads();
            for (int s = 256; s > 0; s >>= 1) {
                if (tid < s) red[tid] = fmaxf(red[tid], red[tid + s]);
                __syncthreads();
            }
            float mx = red[0];
            __syncthreads();
            float ex = (tid < TENC) ? __expf(v - mx) : 0.f;
            red[tid] = ex;
            __syncthreads();
            for (int s = 256; s > 0; s >>= 1) {
                if (tid < s) red[tid] += red[tid + s];
                __syncthreads();
            }
            float inv = 1.f / red[0];
            if (tid < TENC) al[tid] = ex * inv;
            __syncthreads();
            float acc[16];
#pragma unroll
            for (int j = 0; j < 16; ++j) acc[j] = 0.f;
            const float* eb = enc + (size_t)b * TENC * DHH;
            for (int i = 0; i < 16; ++i) {
                int tt = wv * 16 + i;
                float a = al[tt];
                const float* row = eb + (size_t)tt * DHH;
#pragma unroll
                for (int j = 0; j < 16; ++j) acc[j] += a * row[j * 64 + l];
            }
#pragma unroll
            for (int j = 0; j < 16; ++j) pr[wv * 1024 + j * 64 + l] = acc[j];
            __syncthreads();
            {
                int d0 = tid * 2;
                float s0 = 0.f, s1 = 0.f;
#pragma unroll
                for (int w = 0; w < 8; ++w) { s0 += pr[w * 1024 + d0]; s1 += pr[w * 1024 + d0 + 1]; }
                u16 h0 = f2bf(s0), h1 = f2bf(s1);
                u16 l0 = f2bf(s0 - bf2f(h0)), l1 = f2bf(s1 - bf2f(h1));
                st4(xh + (size_t)b * KTOT + d0, (u32)h0 | ((u32)h1 << 16));
                st4(xl + (size_t)b * KTOT + d0, (u32)l0 | ((u32)l1 << 16));
            }
        }
        gbar(flags, gens, bt++);

        // ---------- phase D: gates partials. block = (kq of 8, group of 32) ----------
        {
            int kq = blk & 7, g = blk >> 3;
            // stage x slice [64 rows x 384 cols, hi+lo] -> LDS, pitch 53 units (848B)
            u16* lh = (u16*)smem8;
            u16* ll = lh + 64 * 53 * 8;
            for (int u = tid; u < 3072; u += 512) {
                int row = u / 48, cu = u - row * 48;
                size_t gb = (size_t)row * KTOT + kq * 384 + cu * 8;
                u64 a0 = ld8(xh + gb), a1 = ld8(xh + gb + 4);
                u64 b0 = ld8(xl + gb), b1 = ld8(xl + gb + 4);
                u16* dh = lh + ((row * 53 + cu) << 3);
                u16* dl = ll + ((row * 53 + cu) << 3);
                *(u64*)dh = a0; *(u64*)(dh + 4) = a1;
                *(u64*)dl = b0; *(u64*)(dl + 4) = b1;
            }
            __syncthreads();
            int t0 = (272 * g) >> 5, t1 = (272 * (g + 1)) >> 5;
            for (int nt = t0 + wv; nt < t1; nt += 8) {
                int n0 = nt * 32 + lr;
                const u16* wp0 = Wth + (size_t)n0 * KTOT + kq * 384 + lk4 * 8;
                const u16* wp1 = Wtl + (size_t)n0 * KTOT + kq * 384 + lk4 * 8;
                const u16* wp2 = wp0 + (size_t)16 * KTOT;
                const u16* wp3 = wp1 + (size_t)16 * KTOT;
                f32x4 acc0[4] = {z, z, z, z};
                f32x4 acc1[4] = {z, z, z, z};
                // 4-deep register prefetch ring: ~16 weight loads in flight/wave
                bf16x8 wb[4][4];
#pragma unroll
                for (int p = 0; p < 4; ++p) {
                    wb[p][0] = *(const bf16x8*)(wp0 + p * 32);
                    wb[p][1] = *(const bf16x8*)(wp1 + p * 32);
                    wb[p][2] = *(const bf16x8*)(wp2 + p * 32);
                    wb[p][3] = *(const bf16x8*)(wp3 + p * 32);
                }
#pragma unroll
                for (int i = 0; i < 12; ++i) {
                    bf16x8 bh0 = wb[i & 3][0], bl0 = wb[i & 3][1];
                    bf16x8 bh1 = wb[i & 3][2], bl1 = wb[i & 3][3];
                    if (i < 8) {
                        wb[i & 3][0] = *(const bf16x8*)(wp0 + (i + 4) * 32);
                        wb[i & 3][1] = *(const bf16x8*)(wp1 + (i + 4) * 32);
                        wb[i & 3][2] = *(const bf16x8*)(wp2 + (i + 4) * 32);
                        wb[i & 3][3] = *(const bf16x8*)(wp3 + (i + 4) * 32);
                    }
                    int ub = i * 4 + lk4;
#pragma unroll
                    for (int mf = 0; mf < 4; ++mf) {
                        int row = mf * 16 + lr;
                        bf16x8 ah = *(const bf16x8*)(lh + ((row * 53 + ub) << 3));
                        bf16x8 al_ = *(const bf16x8*)(ll + ((row * 53 + ub) << 3));
                        acc0[mf] = __builtin_amdgcn_mfma_f32_16x16x32_bf16(ah, bh0, acc0[mf], 0, 0, 0);
                        acc0[mf] = __builtin_amdgcn_mfma_f32_16x16x32_bf16(ah, bl0, acc0[mf], 0, 0, 0);
                        acc0[mf] = __builtin_amdgcn_mfma_f32_16x16x32_bf16(al_, bh0, acc0[mf], 0, 0, 0);
                        acc1[mf] = __builtin_amdgcn_mfma_f32_16x16x32_bf16(ah, bh1, acc1[mf], 0, 0, 0);
                        acc1[mf] = __builtin_amdgcn_mfma_f32_16x16x32_bf16(ah, bl1, acc1[mf], 0, 0, 0);
                        acc1[mf] = __builtin_amdgcn_mfma_f32_16x16x32_bf16(al_, bh1, acc1[mf], 0, 0, 0);
                    }
                }
                float* dst = gp + (size_t)kq * 64 * GG;
#pragma unroll
                for (int mf = 0; mf < 4; ++mf)
#pragma unroll
                    for (int r = 0; r < 4; ++r) {
                        int m = mf * 16 + lk4 * 4 + r;
                        stf(&dst[(size_t)m * GG + nt * 32 + lr], acc0[mf][r]);
                        stf(&dst[(size_t)m * GG + nt * 32 + 16 + lr], acc1[mf][r]);
                    }
            }
        }
        gbar(flags, gens, bt++);

        // ---------- phase E: gate reduce + cumsoftmax + ON-LSTM (64b x 4q) ----------
        {
            int b = blk >> 2, q = blk & 3;
            float* g0 = smf;                  // 512
            float* gq = smf + 512;            // 2048
            float* cs1 = smf + 2560;          // 256
            float* cs2 = cs1 + 256;
            float* r1 = cs2 + 256;
            float* r2 = r1 + 256;
            {
                int j = tid;
                float s = bih[j] + bhh[j];
#pragma unroll
                for (int ks = 0; ks < 8; ++ks) s += ldf(&gp[(size_t)(ks * 64 + b) * GG + j]);
                g0[j] = s;
            }
#pragma unroll
            for (int sec = 0; sec < 4; ++sec) {
                int j = 512 + sec * 2048 + q * 512 + tid;
                float s = bih[j] + bhh[j];
#pragma unroll
                for (int ks = 0; ks < 8; ++ks) s += ldf(&gp[(size_t)(ks * 64 + b) * GG + j]);
                gq[sec * 512 + tid] = s;
            }
            __syncthreads();
            float x1 = 0.f, x2 = 0.f;
            if (tid < 256) { x1 = g0[tid]; x2 = g0[NCHN + tid]; r1[tid] = x1; r2[tid] = x2; }
            __syncthreads();
            for (int s = 128; s > 0; s >>= 1) {
                if (tid < s) { r1[tid] = fmaxf(r1[tid], r1[tid + s]); r2[tid] = fmaxf(r2[tid], r2[tid + s]); }
                __syncthreads();
            }
            float m1 = r1[0], m2 = r2[0];
            __syncthreads();
            float e1 = 0.f, e2 = 0.f;
            if (tid < 256) {
                e1 = __expf(x1 - m1); e2 = __expf(x2 - m2);
                r1[tid] = e1; r2[tid] = e2; cs1[tid] = e1; cs2[tid] = e2;
            }
            __syncthreads();
            for (int s = 128; s > 0; s >>= 1) {
                if (tid < s) { r1[tid] += r1[tid + s]; r2[tid] += r2[tid + s]; }
                __syncthreads();
            }
            float inv1 = 1.f / r1[0], inv2 = 1.f / r2[0];
            __syncthreads();
            for (int off = 1; off < NCHN; off <<= 1) {
                float a1 = 0.f, a2 = 0.f;
                if (tid < NCHN && tid >= off) { a1 = cs1[tid - off]; a2 = cs2[tid - off]; }
                __syncthreads();
                if (tid < NCHN) { cs1[tid] += a1; cs2[tid] += a2; }
                __syncthreads();
            }
            float* cb = c + (size_t)b * DVV;
            float* ob = out + ((size_t)b * TDEC + t) * DVV;
            u16* xhb = xh + (size_t)b * KTOT + 1024;
            u16* xlb = xl + (size_t)b * KTOT + 1024;
            if (tid < 256) {
                int i0 = 2 * tid;
                int idx = q * 512 + i0;
                u16 hh[2], lll[2];
#pragma unroll
                for (int e = 0; e < 2; ++e) {
                    int i = i0 + e;
                    int ch = (q * 512 + i) >> 3;
                    float cin = 1.f - cs1[ch] * inv1;
                    float cfg = cs2[ch] * inv2;
                    float ov = cfg * cin;
                    float oo = sigmoid_fast(gq[i]);
                    float gg = tanh_fast(gq[512 + i]);
                    float ii = sigmoid_fast(gq[1024 + i]);
                    float ff = sigmoid_fast(gq[1536 + i]);
                    float fg = ff * ov + (cfg - ov);
                    float ig = ii * ov + (cin - ov);
                    float cy = fg * cb[idx + e] + ig * gg;
                    cb[idx + e] = cy;
                    float hy = oo * tanh_fast(cy);
                    ob[idx + e] = hy;
                    hh[e] = f2bf(hy);
                    lll[e] = f2bf(hy - bf2f(hh[e]));
                }
                st4(xhb + idx, (u32)hh[0] | ((u32)hh[1] << 16));
                st4(xlb + idx, (u32)lll[0] | ((u32)lll[1] << 16));
            }
        }
        gbar(flags, gens, bt++);
    }
}

// ===================== fallback multi-kernel path =====================

__global__ __launch_bounds__(512) void k_mma1(const u16* __restrict__ xh,
                                              const u16* __restrict__ Wta,
                                              float* __restrict__ hWp) {
    __shared__ float red[64 * 68];
    int n0 = blockIdx.x * 64;
    int kseg = blockIdx.y;
    int tid = threadIdx.x;
    int wv = tid >> 6, l = tid & 63;
    int wn = wv & 3, kh = wv >> 2;
    int lr = l & 15, lk = (l >> 4) * 8;
    int n = n0 + wn * 16 + lr;
    const u16* wp = Wta + (size_t)n * 2048 + lk;
    const u16* ap = xh + (size_t)lr * KTOT + 1024 + lk;
    f32x4 z = {0.f, 0.f, 0.f, 0.f};
    f32x4 acc[4] = {z, z, z, z};
    int kbeg = kseg * 256 + kh * 128;
    for (int k = kbeg; k < kbeg + 128; k += 32) {
        bf16x8 bfrag = *(const bf16x8*)(wp + k);
#pragma unroll
        for (int mf = 0; mf < 4; ++mf) {
            bf16x8 a = *(const bf16x8*)(ap + (size_t)mf * 16 * KTOT + k);
            acc[mf] = __builtin_amdgcn_mfma_f32_16x16x32_bf16(a, bfrag, acc[mf], 0, 0, 0);
        }
    }
    int moff = (l >> 4) * 4;
    if (kh == 0) {
#pragma unroll
        for (int mf = 0; mf < 4; ++mf)
#pragma unroll
            for (int r = 0; r < 4; ++r)
                red[(mf * 16 + moff + r) * 68 + wn * 16 + lr] = acc[mf][r];
    }
    __syncthreads();
    if (kh == 1) {
        float* dst = hWp + (size_t)(kseg * 2) * 64 * DHH;
#pragma unroll
        for (int mf = 0; mf < 4; ++mf)
#pragma unroll
            for (int r = 0; r < 4; ++r) {
                int m = mf * 16 + moff + r;
                dst[(size_t)m * DHH + n] = acc[mf][r] + red[m * 68 + wn * 16 + lr];
                hWp[(size_t)((kseg * 2 + 1) * 64 + m) * DHH + n] = 0.f;
            }
    }
}

__global__ __launch_bounds__(256) void k_e_bf(const u16* __restrict__ Pbf,
                                              const float* __restrict__ hWp,
                                              const float* __restrict__ w2,
                                              float* __restrict__ e) {
    int b = blockIdx.x, tg = blockIdx.y;
    __shared__ float hw[DHH];
    __shared__ float w2s[DHH];
    int tid = threadIdx.x;
    {
        float4 s = {0.f, 0.f, 0.f, 0.f};
#pragma unroll
        for (int ks = 0; ks < 16; ++ks) {
            float4 v = *(const float4*)&hWp[(size_t)(ks * 64 + b) * DHH + tid * 4];
            s.x += v.x; s.y += v.y; s.z += v.z; s.w += v.w;
        }
        *(float4*)&hw[tid * 4] = s;
        *(float4*)&w2s[tid * 4] = *(const float4*)&w2[tid * 4];
    }
    __syncthreads();
    int wave = tid >> 6, lane = tid & 63;
    const u16* Pb = Pbf + (size_t)b * TENC * DHH;
    for (int tt = 0; tt < 8; ++tt) {
        int t = tg * 32 + wave * 8 + tt;
        const u16* Pr = Pb + (size_t)t * DHH;
        float s = 0.f;
#pragma unroll
        for (int i = 0; i < 16; ++i) {
            int d = i * 64 + lane;
            s += tanh_fast(bf2f(Pr[d]) + hw[d]) * w2s[d];
        }
#pragma unroll
        for (int off = 32; off > 0; off >>= 1) s += __shfl_down(s, off);
        if (lane == 0) e[b * TENC + t] = s;
    }
}

__global__ __launch_bounds__(256) void k_sc2(const float* __restrict__ e,
                                             const float* __restrict__ enc,
                                             u16* __restrict__ xh,
                                             u16* __restrict__ xl) {
    int b = blockIdx.x, dq = blockIdx.y;
    __shared__ float al[TENC];
    __shared__ float red[256];
    __shared__ float4 pr[4][64];
    int tid = threadIdx.x;
    float v = (tid < TENC) ? e[b * TENC + tid] : -3.0e38f;
    red[tid] = v;
    __syncthreads();
    for (int s = 128; s > 0; s >>= 1) {
        if (tid < s) red[tid] = fmaxf(red[tid], red[tid + s]);
        __syncthreads();
    }
    float mx = red[0];
    __syncthreads();
    float ex = (tid < TENC) ? __expf(v - mx) : 0.f;
    red[tid] = ex;
    __syncthreads();
    for (int s = 128; s > 0; s >>= 1) {
        if (tid < s) red[tid] += red[tid + s];
        __syncthreads();
    }
    float inv = 1.f / red[0];
    if (tid < TENC) al[tid] = ex * inv;
    __syncthreads();
    int w = tid >> 6, l = tid & 63;
    int dbase = dq * 256 + l * 4;
    const float* ep = enc + ((size_t)b * TENC + w * 32) * DHH + dbase;
    float4 acc = {0.f, 0.f, 0.f, 0.f};
#pragma unroll 8
    for (int tt = 0; tt < 32; ++tt) {
        float a = al[w * 32 + tt];
        float4 vv = *(const float4*)(ep + (size_t)tt * DHH);
        acc.x += a * vv.x; acc.y += a * vv.y; acc.z += a * vv.z; acc.w += a * vv.w;
    }
    pr[w][l] = acc;
    __syncthreads();
    if (tid < 64) {
        float4 a0 = pr[0][tid], a1 = pr[1][tid], a2 = pr[2][tid], a3 = pr[3][tid];
        float r0 = a0.x + a1.x + a2.x + a3.x;
        float r1 = a0.y + a1.y + a2.y + a3.y;
        float r2 = a0.z + a1.z + a2.z + a3.z;
        float r3 = a0.w + a1.w + a2.w + a3.w;
        size_t o = (size_t)b * KTOT + dq * 256 + tid * 4;
        u16 h0 = f2bf(r0), h1 = f2bf(r1), h2 = f2bf(r2), h3 = f2bf(r3);
        ushort4 hv = {h0, h1, h2, h3};
        ushort4 lv = {f2bf(r0 - bf2f(h0)), f2bf(r1 - bf2f(h1)),
                      f2bf(r2 - bf2f(h2)), f2bf(r3 - bf2f(h3))};
        *(ushort4*)&xh[o] = hv;
        *(ushort4*)&xl[o] = lv;
    }
}

template <int SEG>
__global__ __launch_bounds__(512) void k_mma3(const u16* __restrict__ xh,
                                              const u16* __restrict__ xl,
                                              const u16* __restrict__ Wh,
                                              const u16* __restrict__ Wl,
                                              float* __restrict__ part) {
    __shared__ float red[64 * 68];
    int n0 = blockIdx.x * 64;
    int kseg = blockIdx.y;
    int tid = threadIdx.x;
    int wv = tid >> 6, l = tid & 63;
    int wn = wv & 3, kh = wv >> 2;
    int lr = l & 15, lk = (l >> 4) * 8;
    int n = n0 + wn * 16 + lr;
    const u16* wph = Wh + (size_t)n * KTOT + lk;
    const u16* wpl = Wl + (size_t)n * KTOT + lk;
    const u16* aph = xh + (size_t)lr * KTOT + lk;
    const u16* apl = xl + (size_t)lr * KTOT + lk;
    f32x4 z = {0.f, 0.f, 0.f, 0.f};
    f32x4 acc[4] = {z, z, z, z};
    const int KSEG = KTOT / SEG;
    const int KH = KSEG / 2;
    int kbeg = kseg * KSEG + kh * KH;
    for (int k = kbeg; k < kbeg + KH; k += 32) {
        bf16x8 bh = *(const bf16x8*)(wph + k);
        bf16x8 bl = *(const bf16x8*)(wpl + k);
#pragma unroll
        for (int mf = 0; mf < 4; ++mf) {
            size_t ao = (size_t)mf * 16 * KTOT + k;
            bf16x8 ah = *(const bf16x8*)(aph + ao);
            bf16x8 al = *(const bf16x8*)(apl + ao);
            acc[mf] = __builtin_amdgcn_mfma_f32_16x16x32_bf16(ah, bh, acc[mf], 0, 0, 0);
            acc[mf] = __builtin_amdgcn_mfma_f32_16x16x32_bf16(ah, bl, acc[mf], 0, 0, 0);
            acc[mf] = __builtin_amdgcn_mfma_f32_16x16x32_bf16(al, bh, acc[mf], 0, 0, 0);
        }
    }
    int moff = (l >> 4) * 4;
    if (kh == 0) {
#pragma unroll
        for (int mf = 0; mf < 4; ++mf)
#pragma unroll
            for (int r = 0; r < 4; ++r)
                red[(mf * 16 + moff + r) * 68 + wn * 16 + lr] = acc[mf][r];
    }
    __syncthreads();
    if (kh == 1) {
        float* dst = part + (size_t)kseg * 64 * GG;
#pragma unroll
        for (int mf = 0; mf < 4; ++mf)
#pragma unroll
            for (int r = 0; r < 4; ++r) {
                int m = mf * 16 + moff + r;
                dst[(size_t)m * GG + n] = acc[mf][r] + red[m * 68 + wn * 16 + lr];
            }
    }
}

__global__ __launch_bounds__(256) void k_pw2(const float* __restrict__ part, int nseg,
                                             const float* __restrict__ bih,
                                             const float* __restrict__ bhh,
                                             u16* __restrict__ xh,
                                             u16* __restrict__ xl,
                                             float* __restrict__ c,
                                             float* __restrict__ out, int t) {
    int b = blockIdx.x;
    __shared__ float g[GG];
    __shared__ float cs1[NCHN], cs2[NCHN], t1[NCHN], t2[NCHN];
    int tid = threadIdx.x;
    for (int p = 0; p < 34; ++p) {
        int j = p * 256 + tid;
        float s = bih[j] + bhh[j];
        for (int ks = 0; ks < nseg; ++ks) s += part[(size_t)(ks * 64 + b) * GG + j];
        g[j] = s;
    }
    __syncthreads();
    float x1 = g[tid], x2 = g[NCHN + tid];
    t1[tid] = x1; t2[tid] = x2;
    __syncthreads();
    for (int s = 128; s > 0; s >>= 1) {
        if (tid < s) { t1[tid] = fmaxf(t1[tid], t1[tid + s]); t2[tid] = fmaxf(t2[tid], t2[tid + s]); }
        __syncthreads();
    }
    float m1 = t1[0], m2 = t2[0];
    __syncthreads();
    float e1 = __expf(x1 - m1), e2 = __expf(x2 - m2);
    t1[tid] = e1; t2[tid] = e2;
    __syncthreads();
    for (int s = 128; s > 0; s >>= 1) {
        if (tid < s) { t1[tid] += t1[tid + s]; t2[tid] += t2[tid + s]; }
        __syncthreads();
    }
    float inv1 = 1.f / t1[0], inv2 = 1.f / t2[0];
    __syncthreads();
    cs1[tid] = e1; cs2[tid] = e2;
    __syncthreads();
    for (int off = 1; off < NCHN; off <<= 1) {
        float a1 = (tid >= off) ? cs1[tid - off] : 0.f;
        float a2 = (tid >= off) ? cs2[tid - off] : 0.f;
        __syncthreads();
        cs1[tid] += a1; cs2[tid] += a2;
        __syncthreads();
    }
    float* cb = c + (size_t)b * DVV;
    float* ob = out + ((size_t)b * TDEC + t) * DVV;
    u16* xhb = xh + (size_t)b * KTOT + 1024;
    u16* xlb = xl + (size_t)b * KTOT + 1024;
    for (int p = 0; p < 8; ++p) {
        int idx = p * 256 + tid;
        int ch = idx >> 3;
        float cin = 1.f - cs1[ch] * inv1;
        float cfg = cs2[ch] * inv2;
        float ov = cfg * cin;
        float oo = sigmoid_fast(g[512 + idx]);
        float gg = tanh_fast(g[2560 + idx]);
        float ii = sigmoid_fast(g[4608 + idx]);
        float ff = sigmoid_fast(g[6656 + idx]);
        float fg = ff * ov + (cfg - ov);
        float ig = ii * ov + (cin - ov);
        float cy = fg * cb[idx] + ig * gg;
        cb[idx] = cy;
        float hy = oo * tanh_fast(cy);
        ob[idx] = hy;
        u16 hh = f2bf(hy);
        xhb[idx] = hh;
        xlb[idx] = f2bf(hy - bf2f(hh));
    }
}

// ===================== launch =====================

extern "C" void kernel_launch(void* const* d_in, const int* in_sizes, int n_in,
                              void* d_out, int out_size, void* d_ws, size_t ws_size,
                              hipStream_t stream) {
    const float* enc    = (const float*)d_in[0];
    const float* W_att1 = (const float*)d_in[2];
    const float* b_att1 = (const float*)d_in[3];
    const float* w_att2 = (const float*)d_in[4];
    const float* W_ih   = (const float*)d_in[5];
    const float* b_ih   = (const float*)d_in[6];
    const float* W_hh   = (const float*)d_in[7];
    const float* b_hh   = (const float*)d_in[8];
    float* out = (float*)d_out;
    float* ws  = (float*)d_ws;
    const float* Wh_att = W_att1 + 1024 * 1024;

    // layout (16B-aligned offsets)
    float* hWp  = ws;                          // 16*64*1024 = 1,048,576 f
    float* ebuf = hWp + 1048576;               // 8,192 f (fallback only)
    float* gp   = ebuf + 8192;                 // 8*64*8704 = 4,456,448 f
    float* c    = gp + 4456448;                // 131,072 f
    int*   bar  = (int*)(c + 131072);          // 8,448 ints
    u16* Pbf = (u16*)(bar + 8448);             // 8,388,608
    u16* xh  = Pbf + 8388608;                  // 196,608
    u16* xl  = xh + 196608;                    // 196,608
    u16* Wth = xl + 196608;                    // 26,738,688
    u16* Wtl = Wth + 26738688;                 // 26,738,688
    u16* Wta = Wtl + 26738688;                 // 2,097,152
    if (ws_size < 151323648ull) return;

    k_cvt<true><<<dim3(136, 48), 256, 0, stream>>>(W_ih, W_hh, 1024, GG, KTOT, Wth, Wtl);
    k_cvt<false><<<dim3(16, 32), 256, 0, stream>>>(Wh_att, Wh_att, 2048, DHH, 2048, Wta, Wta);
    k_Pb<<<dim3(16, 128), 256, 0, stream>>>(enc, W_att1, b_att1, Pbf);
    k_init2<<<768, 256, 0, stream>>>(c, xh, xl, bar);

    void* args[] = {(void*)&Pbf, (void*)&hWp, (void*)&gp, (void*)&c,
                    (void*)&xh, (void*)&xl, (void*)&Wth, (void*)&Wtl, (void*)&Wta,
                    (void*)&enc, (void*)&w_att2, (void*)&b_ih, (void*)&b_hh,
                    (void*)&out, (void*)&bar};
    hipError_t err = hipLaunchCooperativeKernel((const void*)k_decode,
                                                dim3(256), dim3(512), args, 0, stream);
    if (err != hipSuccess) {
        (void)hipGetLastError();
        for (int t = 0; t < TDEC; ++t) {
            k_mma1<<<dim3(16, 8), 512, 0, stream>>>(xh, Wta, hWp);
            k_e_bf<<<dim3(BB, 4), 256, 0, stream>>>(Pbf, hWp, w_att2, ebuf);
            k_sc2<<<dim3(BB, 4), 256, 0, stream>>>(ebuf, enc, xh, xl);
            k_mma3<4><<<dim3(136, 4), 512, 0, stream>>>(xh, xl, Wth, Wtl, gp);
            k_pw2<<<BB, 256, 0, stream>>>(gp, 4, b_ih, b_hh, xh, xl, c, out, t);
        }
    }
}

// Round 9
// 12750.365 us; speedup vs baseline: 1.4832x; 1.4832x over previous
//
#include <hip/hip_runtime.h>
#include <math.h>

#define BB   64
#define TENC 128
#define TDEC 64
#define DHH  1024
#define DVV  2048
#define NCHN 256
#define GG   8704   // 4*DV + 2*NCH
#define KTOT 3072   // DH + DV

typedef unsigned short u16;
typedef unsigned int   u32;
typedef unsigned long long u64;
typedef __bf16 bf16x8 __attribute__((ext_vector_type(8)));
typedef float  f32x4  __attribute__((ext_vector_type(4)));

__device__ __forceinline__ u16 f2bf(float f) {
    unsigned u = __float_as_uint(f);
    unsigned r = (u + 0x7fffu + ((u >> 16) & 1u)) >> 16;
    return (u16)r;
}
__device__ __forceinline__ float bf2f(u16 s) { return __uint_as_float(((unsigned)s) << 16); }
__device__ __forceinline__ float tanh_fast(float x) {
    float xc = fminf(fmaxf(x, -15.f), 15.f);
    float t = __expf(2.f * xc);
    return 1.f - 2.f * __builtin_amdgcn_rcpf(t + 1.f);
}
__device__ __forceinline__ float sigmoid_fast(float x) {
    float xc = fminf(fmaxf(x, -30.f), 30.f);
    return __builtin_amdgcn_rcpf(1.f + __expf(-xc));
}

// ---- sc1 (agent-scope, L2-bypassing) relaxed accessors: no fences ever ----
__device__ __forceinline__ float ldf(const float* p) {
    return __uint_as_float(__hip_atomic_load((u32*)p, __ATOMIC_RELAXED, __HIP_MEMORY_SCOPE_AGENT));
}
__device__ __forceinline__ void stf(float* p, float v) {
    __hip_atomic_store((u32*)p, __float_as_uint(v), __ATOMIC_RELAXED, __HIP_MEMORY_SCOPE_AGENT);
}
__device__ __forceinline__ u64 ld8(const u16* p) {
    return __hip_atomic_load((u64*)p, __ATOMIC_RELAXED, __HIP_MEMORY_SCOPE_AGENT);
}
__device__ __forceinline__ void st4(u16* p, u32 v) {
    __hip_atomic_store((u32*)p, v, __ATOMIC_RELAXED, __HIP_MEMORY_SCOPE_AGENT);
}
// paired-float 8B accessors (halve sc1 transaction count)
__device__ __forceinline__ void st8f(float* p, float a, float b) {
    u64 v = (u64)__float_as_uint(a) | ((u64)__float_as_uint(b) << 32);
    __hip_atomic_store((u64*)p, v, __ATOMIC_RELAXED, __HIP_MEMORY_SCOPE_AGENT);
}
__device__ __forceinline__ float2 ld8f(const float* p) {
    u64 v = __hip_atomic_load((const u64*)p, __ATOMIC_RELAXED, __HIP_MEMORY_SCOPE_AGENT);
    float2 r;
    r.x = __uint_as_float((u32)v);
    r.y = __uint_as_float((u32)(v >> 32));
    return r;
}

// ---- zero-fence grid barrier (round-7, proven) ----
__device__ __forceinline__ void gbar(int* flags, int* gens, int target) {
    __syncthreads();
    int tid = threadIdx.x;
    if (blockIdx.x == 0) {
        if (tid > 0 && tid < 256) {
            while (__hip_atomic_load(flags + tid * 32, __ATOMIC_RELAXED,
                                     __HIP_MEMORY_SCOPE_AGENT) < target)
                __builtin_amdgcn_s_sleep(2);
        }
        __syncthreads();
        if (tid < 8)
            __hip_atomic_store(gens + tid * 32, target, __ATOMIC_RELAXED,
                               __HIP_MEMORY_SCOPE_AGENT);
    } else {
        if (tid == 0) {
            __hip_atomic_store(flags + blockIdx.x * 32, target, __ATOMIC_RELAXED,
                               __HIP_MEMORY_SCOPE_AGENT);
            while (__hip_atomic_load(gens + (blockIdx.x & 7) * 32, __ATOMIC_RELAXED,
                                     __HIP_MEMORY_SCOPE_AGENT) < target)
                __builtin_amdgcn_s_sleep(2);
        }
        __syncthreads();
    }
}

// ===================== precompute kernels =====================

__global__ __launch_bounds__(256) void k_init2(float* c, u16* xh, u16* xl, int* bar) {
    int i = blockIdx.x * 256 + threadIdx.x;   // grid 768 -> 196608
    xh[i] = 0; xl[i] = 0;
    if (i < BB * DVV) c[i] = 0.f;
    if (i < 8448) bar[i] = 0;
}

template <bool LO>
__global__ __launch_bounds__(256) void k_cvt(const float* __restrict__ S1,
                                             const float* __restrict__ S2,
                                             int K1, int N, int K,
                                             u16* __restrict__ Dh,
                                             u16* __restrict__ Dl) {
    __shared__ float t[64][65];
    int n0 = blockIdx.x * 64, k0 = blockIdx.y * 64;
    int tid = threadIdx.x;
    int cn = tid & 63, r4 = tid >> 6;
#pragma unroll
    for (int p = 0; p < 16; ++p) {
        int kk = p * 4 + r4;
        int kg = k0 + kk;
        const float* src = (kg < K1) ? S1 + (size_t)kg * N : S2 + (size_t)(kg - K1) * N;
        t[kk][cn] = src[n0 + cn];
    }
    __syncthreads();
    int ck = tid & 63, n4 = tid >> 6;
#pragma unroll
    for (int p = 0; p < 16; ++p) {
        int nn = p * 4 + n4;
        float w = t[ck][nn];
        u16 hi = f2bf(w);
        size_t o = (size_t)(n0 + nn) * K + k0 + ck;
        Dh[o] = hi;
        if (LO) Dl[o] = f2bf(w - bf2f(hi));
    }
}

__global__ __launch_bounds__(256) void k_Pb(const float* __restrict__ enc,
                                            const float* __restrict__ W1,
                                            const float* __restrict__ b1,
                                            u16* __restrict__ Pb) {
    __shared__ float As[32][68];
    __shared__ float Bs[32][68];
    int j0 = blockIdx.x * 64;
    int m0 = blockIdx.y * 64;
    int tid = threadIdx.x;
    int jg = tid & 15, bg = tid >> 4;
    float acc[4][4] = {};
    for (int k0 = 0; k0 < DHH; k0 += 32) {
#pragma unroll
        for (int p = 0; p < 8; ++p) {
            int r = p * 8 + (tid >> 5);
            int kk = tid & 31;
            As[kk][r] = enc[(size_t)(m0 + r) * DHH + k0 + kk];
        }
#pragma unroll
        for (int p = 0; p < 8; ++p) {
            int kk = p * 4 + (tid >> 6);
            int jl = tid & 63;
            Bs[kk][jl] = W1[(size_t)(k0 + kk) * DHH + j0 + jl];
        }
        __syncthreads();
#pragma unroll
        for (int kk = 0; kk < 32; ++kk) {
            float4 a = *(const float4*)&As[kk][bg * 4];
            float4 b = *(const float4*)&Bs[kk][jg * 4];
            float av[4] = {a.x, a.y, a.z, a.w};
            float bv[4] = {b.x, b.y, b.z, b.w};
#pragma unroll
            for (int i = 0; i < 4; ++i)
#pragma unroll
                for (int j = 0; j < 4; ++j) acc[i][j] += av[i] * bv[j];
        }
        __syncthreads();
    }
    float4 bb = *(const float4*)&b1[j0 + jg * 4];
    float bia[4] = {bb.x, bb.y, bb.z, bb.w};
#pragma unroll
    for (int i = 0; i < 4; ++i) {
        int r = m0 + bg * 4 + i;
        ushort4 sv;
        sv.x = f2bf(acc[i][0] + bia[0]);
        sv.y = f2bf(acc[i][1] + bia[1]);
        sv.z = f2bf(acc[i][2] + bia[2]);
        sv.w = f2bf(acc[i][3] + bia[3]);
        *(ushort4*)&Pb[(size_t)r * DHH + j0 + jg * 4] = sv;
    }
}

// ===================== persistent decode kernel =====================
// Cached (never invalidated): Wth/Wtl/Wta, Pbf, enc, w2, bih, bhh, c, out.
// sc1 (fabric): hWp, xh/xl, gp, flags/gens — all 8B-wide, lane-contiguous.
// MFMA operands SWAPPED (W as A, x as B): each lane's 4 acc entries are 4
// CONSECUTIVE output columns -> paired 8B sc1 stores.

__global__ __launch_bounds__(512) void k_decode(
        const u16* Pbf, float* hWp, float* gp, float* c,
        u16* xh, u16* xl,
        const u16* __restrict__ Wth, const u16* __restrict__ Wtl,
        const u16* __restrict__ Wta,
        const float* __restrict__ enc, const float* __restrict__ w2,
        const float* __restrict__ bih, const float* __restrict__ bhh,
        float* out, int* bar) {
    __shared__ u64 smem8[13568];   // 108,544 B, reused per phase
    float* smf = (float*)smem8;
    int* flags = bar;
    int* gens = bar + 8192;
    int blk = blockIdx.x, tid = threadIdx.x;
    int wv = tid >> 6, l = tid & 63;
    int lr = l & 15, lk4 = l >> 4;
    f32x4 z = {0.f, 0.f, 0.f, 0.f};
    int bt = 1;

    for (int t = 0; t < TDEC; ++t) {
        // ---------- phase A: hW partials (16 d-tiles x 16 ksegs of 128), swapped ----------
        {
            int nt = blk & 15, kseg = blk >> 4;
            int wn = wv & 3, kh = wv >> 2;
            // stage x h-slice [64 rows x 128 cols hi] -> LDS, pitch 21 units (336B)
            u16* lsa = (u16*)smem8;
            for (int u = tid; u < 1024; u += 512) {
                int row = u >> 4, cu = u & 15;
                const u16* gs = xh + (size_t)row * KTOT + 1024 + kseg * 128 + cu * 8;
                u64 a0 = ld8(gs), a1 = ld8(gs + 4);
                u16* d = lsa + ((row * 21 + cu) << 3);
                *(u64*)d = a0; *(u64*)(d + 4) = a1;
            }
            __syncthreads();
            int d0 = nt * 64 + wn * 16;                // this wave's 16-wide d tile
            const u16* wp = Wta + (size_t)(d0 + lr) * 2048 + kseg * 128 + kh * 64 + lk4 * 8;
            bf16x8 w0 = *(const bf16x8*)(wp);
            bf16x8 w1 = *(const bf16x8*)(wp + 32);
            f32x4 acc[4] = {z, z, z, z};               // batch quarters
#pragma unroll
            for (int bq = 0; bq < 4; ++bq) {
                int row = bq * 16 + lr;
                int unit = kh * 8 + lk4;
                bf16x8 xb = *(const bf16x8*)(lsa + ((row * 21 + unit) << 3));
                acc[bq] = __builtin_amdgcn_mfma_f32_16x16x32_bf16(w0, xb, acc[bq], 0, 0, 0);
            }
#pragma unroll
            for (int bq = 0; bq < 4; ++bq) {
                int row = bq * 16 + lr;
                int unit = kh * 8 + lk4 + 4;
                bf16x8 xb = *(const bf16x8*)(lsa + ((row * 21 + unit) << 3));
                acc[bq] = __builtin_amdgcn_mfma_f32_16x16x32_bf16(w1, xb, acc[bq], 0, 0, 0);
            }
            // cross-kh reduce in LDS: red[wn][b 64][d-off 16 pad17]
            float* red = (float*)((char*)smem8 + 21504);
            if (kh == 0) {
#pragma unroll
                for (int bq = 0; bq < 4; ++bq)
#pragma unroll
                    for (int r = 0; r < 4; ++r)
                        red[wn * 1088 + (bq * 16 + lr) * 17 + lk4 * 4 + r] = acc[bq][r];
            }
            __syncthreads();
            if (kh == 1) {
                float* seg = hWp + (size_t)kseg * 64 * DHH;
#pragma unroll
                for (int bq = 0; bq < 4; ++bq) {
                    int b = bq * 16 + lr;
                    float* rb = red + wn * 1088 + b * 17 + lk4 * 4;
                    float v0 = acc[bq][0] + rb[0];
                    float v1 = acc[bq][1] + rb[1];
                    float v2 = acc[bq][2] + rb[2];
                    float v3 = acc[bq][3] + rb[3];
                    float* p = seg + (size_t)b * DHH + d0 + lk4 * 4;
                    st8f(p, v0, v1);
                    st8f(p + 2, v2, v3);
                }
            }
        }
        gbar(flags, gens, bt++);

        // ---------- phase BC (blocks 0..63 = batch b): e, softmax, context ----------
        if (blk < BB) {
            int b = blk;
            float* hw  = smf;             // 1024
            float* w2s = smf + 1024;      // 1024
            float* er  = smf + 2048;      // 128
            float* al  = smf + 2176;      // 128
            float* red = smf + 2304;      // 512
            float* pr  = smf + 2816;      // 8192
            {
                int d0p = tid * 2;
                float s0 = 0.f, s1 = 0.f;
#pragma unroll
                for (int ks = 0; ks < 16; ++ks) {
                    float2 v = ld8f(&hWp[(size_t)(ks * 64 + b) * DHH + d0p]);
                    s0 += v.x; s1 += v.y;
                }
                hw[d0p] = s0; hw[d0p + 1] = s1;
                w2s[d0p] = w2[d0p]; w2s[d0p + 1] = w2[d0p + 1];
            }
            __syncthreads();
            const u16* Pb = Pbf + (size_t)b * TENC * DHH;
#pragma unroll
            for (int i = 0; i < 16; ++i) {
                int tt = wv * 16 + i;
                const u16* Pr = Pb + (size_t)tt * DHH;
                float s = 0.f;
#pragma unroll
                for (int q = 0; q < 16; ++q) {
                    int d = q * 64 + l;
                    s += tanh_fast(bf2f(Pr[d]) + hw[d]) * w2s[d];
                }
#pragma unroll
                for (int off = 32; off > 0; off >>= 1) s += __shfl_down(s, off);
                if (l == 0) er[tt] = s;
            }
            __syncthreads();
            float v = (tid < TENC) ? er[tid] : -3.0e38f;
            red[tid] = v;
            __syncthreads();
            for (int s = 256; s > 0; s >>= 1) {
                if (tid < s) red[tid] = fmaxf(red[tid], red[tid + s]);
                __syncthreads();
            }
            float mx = red[0];
            __syncthreads();
            float ex = (tid < TENC) ? __expf(v - mx) : 0.f;
            red[tid] = ex;
            __syncthreads();
            for (int s = 256; s > 0; s >>= 1) {
                if (tid < s) red[tid] += red[tid + s];
                __syncthreads();
            }
            float inv = 1.f / red[0];
            if (tid < TENC) al[tid] = ex * inv;
            __syncthreads();
            float acc[16];
#pragma unroll
            for (int j = 0; j < 16; ++j) acc[j] = 0.f;
            const float* eb = enc + (size_t)b * TENC * DHH;
            for (int i = 0; i < 16; ++i) {
                int tt = wv * 16 + i;
                float a = al[tt];
                const float* row = eb + (size_t)tt * DHH;
#pragma unroll
                for (int j = 0; j < 16; ++j) acc[j] += a * row[j * 64 + l];
            }
#pragma unroll
            for (int j = 0; j < 16; ++j) pr[wv * 1024 + j * 64 + l] = acc[j];
            __syncthreads();
            {
                int d0 = tid * 2;
                float s0 = 0.f, s1 = 0.f;
#pragma unroll
                for (int w = 0; w < 8; ++w) { s0 += pr[w * 1024 + d0]; s1 += pr[w * 1024 + d0 + 1]; }
                u16 h0 = f2bf(s0), h1 = f2bf(s1);
                u16 l0 = f2bf(s0 - bf2f(h0)), l1 = f2bf(s1 - bf2f(h1));
                st4(xh + (size_t)b * KTOT + d0, (u32)h0 | ((u32)h1 << 16));
                st4(xl + (size_t)b * KTOT + d0, (u32)l0 | ((u32)l1 << 16));
            }
        }
        gbar(flags, gens, bt++);

        // ---------- phase D: gates partials, swapped. block = (kq of 8, group of 32) ----------
        {
            int kq = blk & 7, g = blk >> 3;
            // stage x slice [64 rows x 384 cols, hi+lo] -> LDS, pitch 53 units (848B)
            u16* lh = (u16*)smem8;
            u16* ll = lh + 64 * 53 * 8;
            for (int u = tid; u < 3072; u += 512) {
                int row = u / 48, cu = u - row * 48;
                size_t gb = (size_t)row * KTOT + kq * 384 + cu * 8;
                u64 a0 = ld8(xh + gb), a1 = ld8(xh + gb + 4);
                u64 b0 = ld8(xl + gb), b1 = ld8(xl + gb + 4);
                u16* dh = lh + ((row * 53 + cu) << 3);
                u16* dl = ll + ((row * 53 + cu) << 3);
                *(u64*)dh = a0; *(u64*)(dh + 4) = a1;
                *(u64*)dl = b0; *(u64*)(dl + 4) = b1;
            }
            __syncthreads();
            int t0 = (272 * g) >> 5, t1 = (272 * (g + 1)) >> 5;
            for (int nt = t0 + wv; nt < t1; nt += 8) {
                int j0 = nt * 32;
                const u16* wh0 = Wth + (size_t)(j0 + lr) * KTOT + kq * 384 + lk4 * 8;
                const u16* wl0 = Wtl + (size_t)(j0 + lr) * KTOT + kq * 384 + lk4 * 8;
                const u16* wh1 = wh0 + (size_t)16 * KTOT;
                const u16* wl1 = wl0 + (size_t)16 * KTOT;
                f32x4 acc0[4] = {z, z, z, z};   // j-half 0, batch quarters
                f32x4 acc1[4] = {z, z, z, z};   // j-half 1
                for (int i = 0; i < 12; ++i) {
                    bf16x8 Ah0 = *(const bf16x8*)(wh0 + i * 32);
                    bf16x8 Al0 = *(const bf16x8*)(wl0 + i * 32);
                    bf16x8 Ah1 = *(const bf16x8*)(wh1 + i * 32);
                    bf16x8 Al1 = *(const bf16x8*)(wl1 + i * 32);
                    int ub = i * 4 + lk4;
#pragma unroll
                    for (int bq = 0; bq < 4; ++bq) {
                        int row = bq * 16 + lr;
                        bf16x8 xh_ = *(const bf16x8*)(lh + ((row * 53 + ub) << 3));
                        bf16x8 xl_ = *(const bf16x8*)(ll + ((row * 53 + ub) << 3));
                        acc0[bq] = __builtin_amdgcn_mfma_f32_16x16x32_bf16(Ah0, xh_, acc0[bq], 0, 0, 0);
                        acc0[bq] = __builtin_amdgcn_mfma_f32_16x16x32_bf16(Al0, xh_, acc0[bq], 0, 0, 0);
                        acc0[bq] = __builtin_amdgcn_mfma_f32_16x16x32_bf16(Ah0, xl_, acc0[bq], 0, 0, 0);
                        acc1[bq] = __builtin_amdgcn_mfma_f32_16x16x32_bf16(Ah1, xh_, acc1[bq], 0, 0, 0);
                        acc1[bq] = __builtin_amdgcn_mfma_f32_16x16x32_bf16(Al1, xh_, acc1[bq], 0, 0, 0);
                        acc1[bq] = __builtin_amdgcn_mfma_f32_16x16x32_bf16(Ah1, xl_, acc1[bq], 0, 0, 0);
                    }
                }
                float* dst = gp + (size_t)kq * 64 * GG;
#pragma unroll
                for (int bq = 0; bq < 4; ++bq) {
                    int b = bq * 16 + lr;
                    float* p0 = dst + (size_t)b * GG + j0 + lk4 * 4;
                    st8f(p0, acc0[bq][0], acc0[bq][1]);
                    st8f(p0 + 2, acc0[bq][2], acc0[bq][3]);
                    float* p1 = p0 + 16;
                    st8f(p1, acc1[bq][0], acc1[bq][1]);
                    st8f(p1 + 2, acc1[bq][2], acc1[bq][3]);
                }
            }
        }
        gbar(flags, gens, bt++);

        // ---------- phase E: gate reduce + cumsoftmax + ON-LSTM (64b x 4q) ----------
        {
            int b = blk >> 2, q = blk & 3;
            float* g0 = smf;                  // 512
            float* gq = smf + 512;            // 2048
            float* cs1 = smf + 2560;          // 256
            float* cs2 = cs1 + 256;
            float* r1 = cs2 + 256;
            float* r2 = r1 + 256;
            if (tid < 256) {
                int j2 = tid * 2;
                float s0 = bih[j2] + bhh[j2];
                float s1 = bih[j2 + 1] + bhh[j2 + 1];
#pragma unroll
                for (int ks = 0; ks < 8; ++ks) {
                    float2 v = ld8f(&gp[(size_t)(ks * 64 + b) * GG + j2]);
                    s0 += v.x; s1 += v.y;
                }
                g0[j2] = s0; g0[j2 + 1] = s1;
            }
#pragma unroll
            for (int it = 0; it < 2; ++it) {
                int p = tid + it * 512;           // 1024 pair-tasks
                int sec = p >> 8, pr2 = p & 255;
                int j = 512 + sec * 2048 + q * 512 + pr2 * 2;
                float s0 = bih[j] + bhh[j];
                float s1 = bih[j + 1] + bhh[j + 1];
#pragma unroll
                for (int ks = 0; ks < 8; ++ks) {
                    float2 v = ld8f(&gp[(size_t)(ks * 64 + b) * GG + j]);
                    s0 += v.x; s1 += v.y;
                }
                gq[sec * 512 + pr2 * 2] = s0;
                gq[sec * 512 + pr2 * 2 + 1] = s1;
            }
            __syncthreads();
            float x1 = 0.f, x2 = 0.f;
            if (tid < 256) { x1 = g0[tid]; x2 = g0[NCHN + tid]; r1[tid] = x1; r2[tid] = x2; }
            __syncthreads();
            for (int s = 128; s > 0; s >>= 1) {
                if (tid < s) { r1[tid] = fmaxf(r1[tid], r1[tid + s]); r2[tid] = fmaxf(r2[tid], r2[tid + s]); }
                __syncthreads();
            }
            float m1 = r1[0], m2 = r2[0];
            __syncthreads();
            float e1 = 0.f, e2 = 0.f;
            if (tid < 256) {
                e1 = __expf(x1 - m1); e2 = __expf(x2 - m2);
                r1[tid] = e1; r2[tid] = e2; cs1[tid] = e1; cs2[tid] = e2;
            }
            __syncthreads();
            for (int s = 128; s > 0; s >>= 1) {
                if (tid < s) { r1[tid] += r1[tid + s]; r2[tid] += r2[tid + s]; }
                __syncthreads();
            }
            float inv1 = 1.f / r1[0], inv2 = 1.f / r2[0];
            __syncthreads();
            for (int off = 1; off < NCHN; off <<= 1) {
                float a1 = 0.f, a2 = 0.f;
                if (tid < NCHN && tid >= off) { a1 = cs1[tid - off]; a2 = cs2[tid - off]; }
                __syncthreads();
                if (tid < NCHN) { cs1[tid] += a1; cs2[tid] += a2; }
                __syncthreads();
            }
            float* cb = c + (size_t)b * DVV;
            float* ob = out + ((size_t)b * TDEC + t) * DVV;
            u16* xhb = xh + (size_t)b * KTOT + 1024;
            u16* xlb = xl + (size_t)b * KTOT + 1024;
            if (tid < 256) {
                int i0 = 2 * tid;
                int idx = q * 512 + i0;
                u16 hh[2], lll[2];
#pragma unroll
                for (int e = 0; e < 2; ++e) {
                    int i = i0 + e;
                    int ch = (q * 512 + i) >> 3;
                    float cin = 1.f - cs1[ch] * inv1;
                    float cfg = cs2[ch] * inv2;
                    float ov = cfg * cin;
                    float oo = sigmoid_fast(gq[i]);
                    float gg = tanh_fast(gq[512 + i]);
                    float ii = sigmoid_fast(gq[1024 + i]);
                    float ff = sigmoid_fast(gq[1536 + i]);
                    float fg = ff * ov + (cfg - ov);
                    float ig = ii * ov + (cin - ov);
                    float cy = fg * cb[idx + e] + ig * gg;
                    cb[idx + e] = cy;
                    float hy = oo * tanh_fast(cy);
                    ob[idx + e] = hy;
                    hh[e] = f2bf(hy);
                    lll[e] = f2bf(hy - bf2f(hh[e]));
                }
                st4(xhb + idx, (u32)hh[0] | ((u32)hh[1] << 16));
                st4(xlb + idx, (u32)lll[0] | ((u32)lll[1] << 16));
            }
        }
        gbar(flags, gens, bt++);
    }
}

// ===================== fallback multi-kernel path =====================

__global__ __launch_bounds__(512) void k_mma1(const u16* __restrict__ xh,
                                              const u16* __restrict__ Wta,
                                              float* __restrict__ hWp) {
    __shared__ float red[64 * 68];
    int n0 = blockIdx.x * 64;
    int kseg = blockIdx.y;
    int tid = threadIdx.x;
    int wv = tid >> 6, l = tid & 63;
    int wn = wv & 3, kh = wv >> 2;
    int lr = l & 15, lk = (l >> 4) * 8;
    int n = n0 + wn * 16 + lr;
    const u16* wp = Wta + (size_t)n * 2048 + lk;
    const u16* ap = xh + (size_t)lr * KTOT + 1024 + lk;
    f32x4 z = {0.f, 0.f, 0.f, 0.f};
    f32x4 acc[4] = {z, z, z, z};
    int kbeg = kseg * 256 + kh * 128;
    for (int k = kbeg; k < kbeg + 128; k += 32) {
        bf16x8 bfrag = *(const bf16x8*)(wp + k);
#pragma unroll
        for (int mf = 0; mf < 4; ++mf) {
            bf16x8 a = *(const bf16x8*)(ap + (size_t)mf * 16 * KTOT + k);
            acc[mf] = __builtin_amdgcn_mfma_f32_16x16x32_bf16(a, bfrag, acc[mf], 0, 0, 0);
        }
    }
    int moff = (l >> 4) * 4;
    if (kh == 0) {
#pragma unroll
        for (int mf = 0; mf < 4; ++mf)
#pragma unroll
            for (int r = 0; r < 4; ++r)
                red[(mf * 16 + moff + r) * 68 + wn * 16 + lr] = acc[mf][r];
    }
    __syncthreads();
    if (kh == 1) {
        float* dst = hWp + (size_t)(kseg * 2) * 64 * DHH;
#pragma unroll
        for (int mf = 0; mf < 4; ++mf)
#pragma unroll
            for (int r = 0; r < 4; ++r) {
                int m = mf * 16 + moff + r;
                dst[(size_t)m * DHH + n] = acc[mf][r] + red[m * 68 + wn * 16 + lr];
                hWp[(size_t)((kseg * 2 + 1) * 64 + m) * DHH + n] = 0.f;
            }
    }
}

__global__ __launch_bounds__(256) void k_e_bf(const u16* __restrict__ Pbf,
                                              const float* __restrict__ hWp,
                                              const float* __restrict__ w2,
                                              float* __restrict__ e) {
    int b = blockIdx.x, tg = blockIdx.y;
    __shared__ float hw[DHH];
    __shared__ float w2s[DHH];
    int tid = threadIdx.x;
    {
        float4 s = {0.f, 0.f, 0.f, 0.f};
#pragma unroll
        for (int ks = 0; ks < 16; ++ks) {
            float4 v = *(const float4*)&hWp[(size_t)(ks * 64 + b) * DHH + tid * 4];
            s.x += v.x; s.y += v.y; s.z += v.z; s.w += v.w;
        }
        *(float4*)&hw[tid * 4] = s;
        *(float4*)&w2s[tid * 4] = *(const float4*)&w2[tid * 4];
    }
    __syncthreads();
    int wave = tid >> 6, lane = tid & 63;
    const u16* Pb = Pbf + (size_t)b * TENC * DHH;
    for (int tt = 0; tt < 8; ++tt) {
        int t = tg * 32 + wave * 8 + tt;
        const u16* Pr = Pb + (size_t)t * DHH;
        float s = 0.f;
#pragma unroll
        for (int i = 0; i < 16; ++i) {
            int d = i * 64 + lane;
            s += tanh_fast(bf2f(Pr[d]) + hw[d]) * w2s[d];
        }
#pragma unroll
        for (int off = 32; off > 0; off >>= 1) s += __shfl_down(s, off);
        if (lane == 0) e[b * TENC + t] = s;
    }
}

__global__ __launch_bounds__(256) void k_sc2(const float* __restrict__ e,
                                             const float* __restrict__ enc,
                                             u16* __restrict__ xh,
                                             u16* __restrict__ xl) {
    int b = blockIdx.x, dq = blockIdx.y;
    __shared__ float al[TENC];
    __shared__ float red[256];
    __shared__ float4 pr[4][64];
    int tid = threadIdx.x;
    float v = (tid < TENC) ? e[b * TENC + tid] : -3.0e38f;
    red[tid] = v;
    __syncthreads();
    for (int s = 128; s > 0; s >>= 1) {
        if (tid < s) red[tid] = fmaxf(red[tid], red[tid + s]);
        __syncthreads();
    }
    float mx = red[0];
    __syncthreads();
    float ex = (tid < TENC) ? __expf(v - mx) : 0.f;
    red[tid] = ex;
    __syncthreads();
    for (int s = 128; s > 0; s >>= 1) {
        if (tid < s) red[tid] += red[tid + s];
        __syncthreads();
    }
    float inv = 1.f / red[0];
    if (tid < TENC) al[tid] = ex * inv;
    __syncthreads();
    int w = tid >> 6, l = tid & 63;
    int dbase = dq * 256 + l * 4;
    const float* ep = enc + ((size_t)b * TENC + w * 32) * DHH + dbase;
    float4 acc = {0.f, 0.f, 0.f, 0.f};
#pragma unroll 8
    for (int tt = 0; tt < 32; ++tt) {
        float a = al[w * 32 + tt];
        float4 vv = *(const float4*)(ep + (size_t)tt * DHH);
        acc.x += a * vv.x; acc.y += a * vv.y; acc.z += a * vv.z; acc.w += a * vv.w;
    }
    pr[w][l] = acc;
    __syncthreads();
    if (tid < 64) {
        float4 a0 = pr[0][tid], a1 = pr[1][tid], a2 = pr[2][tid], a3 = pr[3][tid];
        float r0 = a0.x + a1.x + a2.x + a3.x;
        float r1 = a0.y + a1.y + a2.y + a3.y;
        float r2 = a0.z + a1.z + a2.z + a3.z;
        float r3 = a0.w + a1.w + a2.w + a3.w;
        size_t o = (size_t)b * KTOT + dq * 256 + tid * 4;
        u16 h0 = f2bf(r0), h1 = f2bf(r1), h2 = f2bf(r2), h3 = f2bf(r3);
        ushort4 hv = {h0, h1, h2, h3};
        ushort4 lv = {f2bf(r0 - bf2f(h0)), f2bf(r1 - bf2f(h1)),
                      f2bf(r2 - bf2f(h2)), f2bf(r3 - bf2f(h3))};
        *(ushort4*)&xh[o] = hv;
        *(ushort4*)&xl[o] = lv;
    }
}

template <int SEG>
__global__ __launch_bounds__(512) void k_mma3(const u16* __restrict__ xh,
                                              const u16* __restrict__ xl,
                                              const u16* __restrict__ Wh,
                                              const u16* __restrict__ Wl,
                                              float* __restrict__ part) {
    __shared__ float red[64 * 68];
    int n0 = blockIdx.x * 64;
    int kseg = blockIdx.y;
    int tid = threadIdx.x;
    int wv = tid >> 6, l = tid & 63;
    int wn = wv & 3, kh = wv >> 2;
    int lr = l & 15, lk = (l >> 4) * 8;
    int n = n0 + wn * 16 + lr;
    const u16* wph = Wh + (size_t)n * KTOT + lk;
    const u16* wpl = Wl + (size_t)n * KTOT + lk;
    const u16* aph = xh + (size_t)lr * KTOT + lk;
    const u16* apl = xl + (size_t)lr * KTOT + lk;
    f32x4 z = {0.f, 0.f, 0.f, 0.f};
    f32x4 acc[4] = {z, z, z, z};
    const int KSEG = KTOT / SEG;
    const int KH = KSEG / 2;
    int kbeg = kseg * KSEG + kh * KH;
    for (int k = kbeg; k < kbeg + KH; k += 32) {
        bf16x8 bh = *(const bf16x8*)(wph + k);
        bf16x8 bl = *(const bf16x8*)(wpl + k);
#pragma unroll
        for (int mf = 0; mf < 4; ++mf) {
            size_t ao = (size_t)mf * 16 * KTOT + k;
            bf16x8 ah = *(const bf16x8*)(aph + ao);
            bf16x8 al = *(const bf16x8*)(apl + ao);
            acc[mf] = __builtin_amdgcn_mfma_f32_16x16x32_bf16(ah, bh, acc[mf], 0, 0, 0);
            acc[mf] = __builtin_amdgcn_mfma_f32_16x16x32_bf16(ah, bl, acc[mf], 0, 0, 0);
            acc[mf] = __builtin_amdgcn_mfma_f32_16x16x32_bf16(al, bh, acc[mf], 0, 0, 0);
        }
    }
    int moff = (l >> 4) * 4;
    if (kh == 0) {
#pragma unroll
        for (int mf = 0; mf < 4; ++mf)
#pragma unroll
            for (int r = 0; r < 4; ++r)
                red[(mf * 16 + moff + r) * 68 + wn * 16 + lr] = acc[mf][r];
    }
    __syncthreads();
    if (kh == 1) {
        float* dst = part + (size_t)kseg * 64 * GG;
#pragma unroll
        for (int mf = 0; mf < 4; ++mf)
#pragma unroll
            for (int r = 0; r < 4; ++r) {
                int m = mf * 16 + moff + r;
                dst[(size_t)m * GG + n] = acc[mf][r] + red[m * 68 + wn * 16 + lr];
            }
    }
}

__global__ __launch_bounds__(256) void k_pw2(const float* __restrict__ part, int nseg,
                                             const float* __restrict__ bih,
                                             const float* __restrict__ bhh,
                                             u16* __restrict__ xh,
                                             u16* __restrict__ xl,
                                             float* __restrict__ c,
                                             float* __restrict__ out, int t) {
    int b = blockIdx.x;
    __shared__ float g[GG];
    __shared__ float cs1[NCHN], cs2[NCHN], t1[NCHN], t2[NCHN];
    int tid = threadIdx.x;
    for (int p = 0; p < 34; ++p) {
        int j = p * 256 + tid;
        float s = bih[j] + bhh[j];
        for (int ks = 0; ks < nseg; ++ks) s += part[(size_t)(ks * 64 + b) * GG + j];
        g[j] = s;
    }
    __syncthreads();
    float x1 = g[tid], x2 = g[NCHN + tid];
    t1[tid] = x1; t2[tid] = x2;
    __syncthreads();
    for (int s = 128; s > 0; s >>= 1) {
        if (tid < s) { t1[tid] = fmaxf(t1[tid], t1[tid + s]); t2[tid] = fmaxf(t2[tid], t2[tid + s]); }
        __syncthreads();
    }
    float m1 = t1[0], m2 = t2[0];
    __syncthreads();
    float e1 = __expf(x1 - m1), e2 = __expf(x2 - m2);
    t1[tid] = e1; t2[tid] = e2;
    __syncthreads();
    for (int s = 128; s > 0; s >>= 1) {
        if (tid < s) { t1[tid] += t1[tid + s]; t2[tid] += t2[tid + s]; }
        __syncthreads();
    }
    float inv1 = 1.f / t1[0], inv2 = 1.f / t2[0];
    __syncthreads();
    cs1[tid] = e1; cs2[tid] = e2;
    __syncthreads();
    for (int off = 1; off < NCHN; off <<= 1) {
        float a1 = (tid >= off) ? cs1[tid - off] : 0.f;
        float a2 = (tid >= off) ? cs2[tid - off] : 0.f;
        __syncthreads();
        cs1[tid] += a1; cs2[tid] += a2;
        __syncthreads();
    }
    float* cb = c + (size_t)b * DVV;
    float* ob = out + ((size_t)b * TDEC + t) * DVV;
    u16* xhb = xh + (size_t)b * KTOT + 1024;
    u16* xlb = xl + (size_t)b * KTOT + 1024;
    for (int p = 0; p < 8; ++p) {
        int idx = p * 256 + tid;
        int ch = idx >> 3;
        float cin = 1.f - cs1[ch] * inv1;
        float cfg = cs2[ch] * inv2;
        float ov = cfg * cin;
        float oo = sigmoid_fast(g[512 + idx]);
        float gg = tanh_fast(g[2560 + idx]);
        float ii = sigmoid_fast(g[4608 + idx]);
        float ff = sigmoid_fast(g[6656 + idx]);
        float fg = ff * ov + (cfg - ov);
        float ig = ii * ov + (cin - ov);
        float cy = fg * cb[idx] + ig * gg;
        cb[idx] = cy;
        float hy = oo * tanh_fast(cy);
        ob[idx] = hy;
        u16 hh = f2bf(hy);
        xhb[idx] = hh;
        xlb[idx] = f2bf(hy - bf2f(hh));
    }
}

// ===================== launch =====================

extern "C" void kernel_launch(void* const* d_in, const int* in_sizes, int n_in,
                              void* d_out, int out_size, void* d_ws, size_t ws_size,
                              hipStream_t stream) {
    const float* enc    = (const float*)d_in[0];
    const float* W_att1 = (const float*)d_in[2];
    const float* b_att1 = (const float*)d_in[3];
    const float* w_att2 = (const float*)d_in[4];
    const float* W_ih   = (const float*)d_in[5];
    const float* b_ih   = (const float*)d_in[6];
    const float* W_hh   = (const float*)d_in[7];
    const float* b_hh   = (const float*)d_in[8];
    float* out = (float*)d_out;
    float* ws  = (float*)d_ws;
    const float* Wh_att = W_att1 + 1024 * 1024;

    // layout (16B-aligned offsets)
    float* hWp  = ws;                          // 16*64*1024 = 1,048,576 f
    float* ebuf = hWp + 1048576;               // 8,192 f (fallback only)
    float* gp   = ebuf + 8192;                 // 8*64*8704 = 4,456,448 f
    float* c    = gp + 4456448;                // 131,072 f
    int*   bar  = (int*)(c + 131072);          // 8,448 ints
    u16* Pbf = (u16*)(bar + 8448);             // 8,388,608
    u16* xh  = Pbf + 8388608;                  // 196,608
    u16* xl  = xh + 196608;                    // 196,608
    u16* Wth = xl + 196608;                    // 26,738,688
    u16* Wtl = Wth + 26738688;                 // 26,738,688
    u16* Wta = Wtl + 26738688;                 // 2,097,152
    if (ws_size < 151323648ull) return;

    k_cvt<true><<<dim3(136, 48), 256, 0, stream>>>(W_ih, W_hh, 1024, GG, KTOT, Wth, Wtl);
    k_cvt<false><<<dim3(16, 32), 256, 0, stream>>>(Wh_att, Wh_att, 2048, DHH, 2048, Wta, Wta);
    k_Pb<<<dim3(16, 128), 256, 0, stream>>>(enc, W_att1, b_att1, Pbf);
    k_init2<<<768, 256, 0, stream>>>(c, xh, xl, bar);

    void* args[] = {(void*)&Pbf, (void*)&hWp, (void*)&gp, (void*)&c,
                    (void*)&xh, (void*)&xl, (void*)&Wth, (void*)&Wtl, (void*)&Wta,
                    (void*)&enc, (void*)&w_att2, (void*)&b_ih, (void*)&b_hh,
                    (void*)&out, (void*)&bar};
    hipError_t err = hipLaunchCooperativeKernel((const void*)k_decode,
                                                dim3(256), dim3(512), args, 0, stream);
    if (err != hipSuccess) {
        (void)hipGetLastError();
        for (int t = 0; t < TDEC; ++t) {
            k_mma1<<<dim3(16, 8), 512, 0, stream>>>(xh, Wta, hWp);
            k_e_bf<<<dim3(BB, 4), 256, 0, stream>>>(Pbf, hWp, w_att2, ebuf);
            k_sc2<<<dim3(BB, 4), 256, 0, stream>>>(ebuf, enc, xh, xl);
            k_mma3<4><<<dim3(136, 4), 512, 0, stream>>>(xh, xl, Wth, Wtl, gp);
            k_pw2<<<BB, 256, 0, stream>>>(gp, 4, b_ih, b_hh, xh, xl, c, out, t);
        }
    }
}